// Round 9
// baseline (497.228 us; speedup 1.0000x reference)
//
#include <hip/hip_runtime.h>
#include <hip/hip_bf16.h>
#include <stdint.h>

// GroupedQAttention on MI355X.
// cast x->bf16, transpose-cast weights -> bf16 BT,
// GEMM1 (256^2 8-phase/2-tile, 32x32x16 MFMA, constant LDS offsets) -> qkvw,
// fused tiny-attention*w -> ow (bf16), GEMM2 (same) -> fp32 out.
// R3: row-major XCD chunking + plain stores. R5: supertile (kept).
// R7 FAILED: vmcnt is PER-WAVE; staged-region reads must follow {VM;BAR}.
// R8: correct gates at ph4/ph8 before BAR (kept verbatim). R9: swap MFMA
// shape 16x16x32 -> 32x32x16 (µbench 2495 vs 2075 TF, +20% FLOP/cyc) with
// identical schedule, read counts, swizzle, and register budget.

typedef __bf16 bf16;
typedef __bf16 bf16x8 __attribute__((ext_vector_type(8)));
typedef float f32x16 __attribute__((ext_vector_type(16)));

__device__ __forceinline__ void gload16(const bf16* g, bf16* l) {
  __builtin_amdgcn_global_load_lds(
      (const __attribute__((address_space(1))) void*)g,
      (__attribute__((address_space(3))) void*)l, 16, 0, 0);
}

#define BAR() asm volatile("s_barrier" ::: "memory")
#define SB() __builtin_amdgcn_sched_barrier(0)
#define LGKM0 asm volatile("s_waitcnt lgkmcnt(0)" ::: "memory")
#define VM4 asm volatile("s_waitcnt vmcnt(4)" ::: "memory")
#define VM0 asm volatile("s_waitcnt vmcnt(0)" ::: "memory")
#define PRIO1 __builtin_amdgcn_s_setprio(1)
#define PRIO0 __builtin_amdgcn_s_setprio(0)

// ---------- 256x256-tile GEMM: C[M][N] = A[M][1024] * BT[N][1024]^T ----------
// 512 threads = 8 waves (2Mx4N). BK=64; 16 K-tiles = 8 pairs (E=2j, O=2j+1).
// LDS 128KiB, constant offsets:
//   A0lo 0      A0hi 16384   A1lo 32768  A1hi 49152    (A0=E tiles, A1=O)
//   B0lo 65536  B0hi 81920   B1lo 98304  B1hi 114688   (B0=E, B1=O)
// Swizzle involution on [128][64]bf16 halves: byte ^= ((byte>>7)&7)<<4.
// MFMA 32x32x16: A row=lane&31, k=(lane>>5)*8+e (b128/lane per ks);
//   C/D col=lane&31, row=(reg&3)+8*(reg>>2)+4*(lane>>5).
// Per wave (128x64): 4 m-tiles x 2 n-tiles x 4 ks = 32 MFMA/K-tile; split as
// quadrant phases (mq in {0,1}: 2 m-tiles; nh in {0,1}: 1 n-tile) = 8 MFMA.
// Phase = [reads][stage][gate?][BAR][lgkm0][8 MFMA][BAR]. (schedule == R8)
//  ph1: rd a0<-A0mq0 (8), b0<-B0nh0 (4) | st B(O)lo | MFMA(0,0)
//  ph2: rd a1<-A0mq1 (8)               | st B(O)hi | MFMA(1,0)
//  ph3: rd b1<-B0nh1 (4)               | st A(E+2)lo | MFMA(1,1)
//  ph4:                                | st A(E+2)hi, VM4 | MFMA(0,1)
//  ph5-8: same on A1/B1, staging B(E+2), A(O+2); ph8 gate VM4.
// RAW/WAR ledger identical to R8 (gates {VM;BAR} cover the next phases'
// reads; stages follow victim's last-read LGKM0 + BAR). Last pair: ph4 VM0.
#define READ_A8(dst, base, mq)                                                \
  {                                                                           \
    _Pragma("unroll") for (int i = 0; i < 2; ++i)                             \
        _Pragma("unroll") for (int ks = 0; ks < 4; ++ks)                      \
            dst[i][ks] = *(const bf16x8*)(lds + (base) + ahalf +              \
                                          ((mq)*64 + i * 32 + arow) * 128 +   \
                                          ((ks * 32 + fkb) ^ xo));            \
  }
#define READ_B4(dst, base, nh)                                                \
  {                                                                           \
    _Pragma("unroll") for (int ks = 0; ks < 4; ++ks)                          \
        dst[ks] = *(const bf16x8*)(lds + (base) + bhalf +                     \
                                   (bro + (nh)*32 + arow) * 128 +             \
                                   ((ks * 32 + fkb) ^ xo));                   \
  }
#define MFMA_Q(arr, bv, mq)                                                   \
  {                                                                           \
    _Pragma("unroll") for (int ks = 0; ks < 4; ++ks)                          \
        _Pragma("unroll") for (int i = 0; i < 2; ++i)                         \
            accq[(mq)*2 + i] = __builtin_amdgcn_mfma_f32_32x32x16_bf16(       \
                arr[i][ks], bv[ks], accq[(mq)*2 + i], 0, 0, 0);               \
  }
#define STAGE(gsrc, lbase)                                                    \
  {                                                                           \
    gload16((gsrc), (bf16*)(lds + (lbase) + wv * 1024));                      \
    gload16((gsrc) + 64 * 1024, (bf16*)(lds + (lbase) + 8192 + wv * 1024));   \
  }

template <typename OutT>
__global__ __launch_bounds__(512, 2)
void gemm256(const bf16* __restrict__ A, const bf16* __restrict__ BT,
             OutT* __restrict__ C, int N, int super) {
  constexpr int K = 1024;
  __shared__ __align__(16) char smem[131072];
  char* lds = smem;

  const int tid = threadIdx.x;
  const int lane = tid & 63;
  const int wv = tid >> 6;
  const int wr = wv >> 2;  // 0..1
  const int wc = wv & 3;   // 0..3

  // XCD chunking + 8x4 supertiles (R5: FETCH 307->204MB)
  const int gx = gridDim.x;
  const int nwg = gx * gridDim.y;
  const int bid = blockIdx.y * gx + blockIdx.x;
  const int xcd = bid & 7;
  const int l = bid >> 3;
  long trow, tcol;
  if (super) {  // requires (nwg/8)/gx == 16 and gx%4==0
    const int s = l >> 5, i = l & 31;
    const int colS = gx >> 2;
    trow = xcd * 16 + (s / colS) * 8 + (i >> 2);
    tcol = (s % colS) * 4 + (i & 3);
  } else {
    const int swz = xcd * (nwg >> 3) + l;
    trow = swz / gx;
    tcol = swz % gx;
  }
  const long row0 = trow * 256;
  const long col0 = tcol * 256;

  // staging source (pre-swizzled so linear global_load_lds dest == swizzled layout)
  const int srow = tid >> 3;  // 0..63
  const int scol = (((tid & 7) * 16) ^ ((srow & 7) << 4)) >> 1;  // elements
  const bf16* gA = A + (row0 + srow) * K + scol;
  const bf16* gB = BT + (col0 + srow) * K + scol;

  // fragment read addressing (32x32x16)
  const int arow = lane & 31;
  const int fkb = (lane >> 5) * 16;  // byte offset of k-half within ks slice
  const int xo = (arow & 7) << 4;
  const int bro = (wc & 1) * 64;
  const int ahalf = wr * 16384;
  const int bhalf = (wc >> 1) * 16384;

  bf16x8 a0[2][4], a1[2][4], b0[4], b1[4];
  f32x16 accq[4] = {};   // [m-tile 0..3] for nh=0
  f32x16 accq1[4] = {};  // for nh=1

  // prologue: A(0)->A0, B(0)->B0, A(1)->A1 (12 loads); VM4 leaves A(1)x4,
  // drains A(0),B(0); BAR makes them globally visible for ph1-3 reads.
  STAGE(gA, 0); STAGE(gA + 131072, 16384);
  STAGE(gB, 65536); STAGE(gB + 131072, 81920);
  STAGE(gA + 64, 32768); STAGE(gA + 131072 + 64, 49152);
  VM4;
  SB(); BAR(); SB();

  const bf16* gAm = gA;
  const bf16* gBm = gB;
  for (int j = 0; j < 8; ++j) {
    const bool nl = (j < 7);
    // ph1
    READ_A8(a0, 0, 0); READ_B4(b0, 65536, 0);
    STAGE(gBm + 64, 98304);
    SB(); BAR(); LGKM0; SB();
    PRIO1; MFMA_Q(a0, b0, 0); PRIO0; SB(); BAR();
    // ph2
    READ_A8(a1, 0, 1);
    STAGE(gBm + 131072 + 64, 114688);
    SB(); BAR(); LGKM0; SB();
    PRIO1; MFMA_Q(a1, b0, 1); PRIO0; SB(); BAR();
    // ph3
    READ_B4(b1, 65536, 1);
    if (nl) STAGE(gAm + 128, 0);
    SB(); BAR(); LGKM0; SB();
    {
      f32x16* accq_ = accq1;
      PRIO1;
      _Pragma("unroll") for (int ks = 0; ks < 4; ++ks)
          _Pragma("unroll") for (int i = 0; i < 2; ++i)
              accq_[2 + i] = __builtin_amdgcn_mfma_f32_32x32x16_bf16(
                  a1[i][ks], b1[ks], accq_[2 + i], 0, 0, 0);
      PRIO0;
    }
    SB(); BAR();
    // ph4: gate before BAR (covers A1,B1 for ph5-7)
    if (nl) {
      STAGE(gAm + 131072 + 128, 16384);
      VM4;
    } else {
      VM0;
    }
    SB(); BAR(); LGKM0; SB();
    {
      f32x16* accq_ = accq1;
      PRIO1;
      _Pragma("unroll") for (int ks = 0; ks < 4; ++ks)
          _Pragma("unroll") for (int i = 0; i < 2; ++i)
              accq_[i] = __builtin_amdgcn_mfma_f32_32x32x16_bf16(
                  a0[i][ks], b1[ks], accq_[i], 0, 0, 0);
      PRIO0;
    }
    SB(); BAR();
    // ph5
    READ_A8(a0, 32768, 0); READ_B4(b0, 98304, 0);
    if (nl) STAGE(gBm + 128, 65536);
    SB(); BAR(); LGKM0; SB();
    PRIO1; MFMA_Q(a0, b0, 0); PRIO0; SB(); BAR();
    // ph6
    READ_A8(a1, 32768, 1);
    if (nl) STAGE(gBm + 131072 + 128, 81920);
    SB(); BAR(); LGKM0; SB();
    PRIO1; MFMA_Q(a1, b0, 1); PRIO0; SB(); BAR();
    // ph7
    READ_B4(b1, 98304, 1);
    if (nl) STAGE(gAm + 192, 32768);
    SB(); BAR(); LGKM0; SB();
    {
      f32x16* accq_ = accq1;
      PRIO1;
      _Pragma("unroll") for (int ks = 0; ks < 4; ++ks)
          _Pragma("unroll") for (int i = 0; i < 2; ++i)
              accq_[2 + i] = __builtin_amdgcn_mfma_f32_32x32x16_bf16(
                  a1[i][ks], b1[ks], accq_[2 + i], 0, 0, 0);
      PRIO0;
    }
    SB(); BAR();
    // ph8: gate before BAR (covers A0,B0 for next pair's ph1-3)
    if (nl) {
      STAGE(gAm + 131072 + 192, 49152);
      VM4;
    }
    SB(); BAR(); LGKM0; SB();
    {
      f32x16* accq_ = accq1;
      PRIO1;
      _Pragma("unroll") for (int ks = 0; ks < 4; ++ks)
          _Pragma("unroll") for (int i = 0; i < 2; ++i)
              accq_[i] = __builtin_amdgcn_mfma_f32_32x32x16_bf16(
                  a0[i][ks], b1[ks], accq_[i], 0, 0, 0);
      PRIO0;
    }
    SB(); BAR();
    gAm += 128;
    gBm += 128;
  }

  // epilogue: C/D 32x32 layout col=lane&31, row=(reg&3)+8*(reg>>2)+4*(lane>>5)
  const int ccol = lane & 31;
  const int rbase = 4 * (lane >> 5);
  const long rb = row0 + wr * 128;
  const long cb = col0 + wc * 64;
#pragma unroll
  for (int mt = 0; mt < 4; ++mt) {
#pragma unroll
    for (int reg = 0; reg < 16; ++reg) {
      const long r = rb + mt * 32 + rbase + (reg & 3) + 8 * (reg >> 2);
      C[r * (long)N + cb + ccol] = (OutT)accq[mt][reg];
      C[r * (long)N + cb + 32 + ccol] = (OutT)accq1[mt][reg];
    }
  }
}

// ---------------- fused tiny attention ----------------
__device__ __forceinline__ void load16f(const bf16* p, float* f) {
  const uint4* u = (const uint4*)p;
  uint4 a = u[0], b = u[1];
  uint32_t w[8] = {a.x, a.y, a.z, a.w, b.x, b.y, b.z, b.w};
#pragma unroll
  for (int j = 0; j < 8; ++j) {
    f[2 * j] = __uint_as_float(w[j] << 16);
    f[2 * j + 1] = __uint_as_float(w[j] & 0xffff0000u);
  }
}

// block = (s_hi, g, bz); 256 threads = 16 s_lo x 16 h1
__global__ __launch_bounds__(256)
void attn_fuse(const bf16* __restrict__ qkvw, bf16* __restrict__ ow,
               int b0, long bstride) {
  __shared__ bf16 data[16 * 1024];
  const int s_hi = blockIdx.x;
  const int g = blockIdx.y;
  const int bz = blockIdx.z;
  const int b = b0 + bz;
  const bf16* base = qkvw + (long)bz * bstride;
  const int tid = threadIdx.x;

#pragma unroll
  for (int i = 0; i < 8; ++i) {
    int c = tid + i * 256;
    int h = c >> 7;
    int col = (c & 127) * 8;
    *(uint4*)&data[h * 1024 + col] =
        *(const uint4*)(base + (long)(h * 256 + s_hi) * 4096 + g * 1024 + col);
  }
  __syncthreads();

  const int s_lo = tid >> 4;
  const int h1 = tid & 15;
  const int off = s_lo * 16;

  float q[16], p[16], o[16];
  load16f(&data[h1 * 1024 + off], q);

  float mx = -1e30f;
#pragma unroll
  for (int h2 = 0; h2 < 16; ++h2) {
    float kf[16];
    load16f(&data[h2 * 1024 + 256 + off], kf);
    float s = 0.f;
#pragma unroll
    for (int d = 0; d < 16; ++d) s += q[d] * kf[d];
    s *= 0.25f;  // HD^-0.5, HD=16
    p[h2] = s;
    mx = fmaxf(mx, s);
  }
  float sum = 0.f;
#pragma unroll
  for (int h2 = 0; h2 < 16; ++h2) {
    float e = __expf(p[h2] - mx);
    p[h2] = e;
    sum += e;
  }
  const float inv = 1.f / sum;
#pragma unroll
  for (int d = 0; d < 16; ++d) o[d] = 0.f;
#pragma unroll
  for (int h2 = 0; h2 < 16; ++h2) {
    float vf[16];
    load16f(&data[h2 * 1024 + 512 + off], vf);
    const float av = p[h2] * inv;
#pragma unroll
    for (int d = 0; d < 16; ++d) o[d] += av * vf[d];
  }
  float wf[16];
  load16f(&data[h1 * 1024 + 768 + off], wf);

  const int bp = g * 8 + b;  // concat index along axis 0
  const long R = (long)(bp >> 2) * 4096 + (bp & 3) * 1024 + h1 * 64 + (s_hi >> 2);
  const int cbo = (s_hi & 3) * 256 + off;
  union { uint4 u[2]; bf16 hh[16]; } st;
#pragma unroll
  for (int d = 0; d < 16; ++d) st.hh[d] = (bf16)(o[d] * wf[d]);
  uint4* dst = (uint4*)&ow[R * 1024 + cbo];
  dst[0] = st.u[0];
  dst[1] = st.u[1];
}

// ---------------- casts ----------------
__global__ __launch_bounds__(256)
void cast_x_kernel(const float* __restrict__ in, bf16* __restrict__ out, long n4) {
  long i = (long)blockIdx.x * 256 + threadIdx.x;
  if (i >= n4) return;
  float4 v = ((const float4*)in)[i];
  union { uint2 d; bf16 h[4]; } r;
  r.h[0] = (bf16)v.x; r.h[1] = (bf16)v.y; r.h[2] = (bf16)v.z; r.h[3] = (bf16)v.w;
  ((uint2*)out)[i] = r.d;
}

// out[C][R] = bf16(in[R][C])  (transpose-cast, 64x64 tiles)
__global__ __launch_bounds__(256)
void tcast_kernel(const float* __restrict__ in, bf16* __restrict__ out, int R, int C) {
  __shared__ float t[64][65];
  const int c0 = blockIdx.x * 64, r0 = blockIdx.y * 64;
  const int lr = threadIdx.x >> 6;
  const int lc = threadIdx.x & 63;
#pragma unroll
  for (int i = 0; i < 16; ++i)
    t[lr + i * 4][lc] = in[(long)(r0 + lr + i * 4) * C + c0 + lc];
  __syncthreads();
#pragma unroll
  for (int i = 0; i < 16; ++i) {
    int oc = lr + i * 4;
    out[(long)(c0 + oc) * R + r0 + lc] = (bf16)t[lc][oc];
  }
}

// ---------------- launch ----------------
extern "C" void kernel_launch(void* const* d_in, const int* in_sizes, int n_in,
                              void* d_out, int out_size, void* d_ws, size_t ws_size,
                              hipStream_t stream) {
  const float* x = (const float*)d_in[0];
  const float* w_qkvw = (const float*)d_in[1];
  const float* w_out = (const float*)d_in[2];
  float* out = (float*)d_out;

  char* ws = (char*)d_ws;
  size_t off = 0;
  bf16* x_bf = (bf16*)(ws + off); off += (size_t)32768 * 1024 * 2;
  bf16* bt1  = (bf16*)(ws + off); off += (size_t)4096 * 1024 * 2;
  bf16* bt2  = (bf16*)(ws + off); off += (size_t)1024 * 1024 * 2;
  bf16* owb  = (bf16*)(ws + off); off += (size_t)32768 * 1024 * 2;
  bf16* qk   = (bf16*)(ws + off);
  const size_t rem = ws_size > off ? ws_size - off : 0;
  const size_t full_need = (size_t)32768 * 4096 * 2;

  cast_x_kernel<<<32768, 256, 0, stream>>>(x, x_bf, (long)8388608);
  tcast_kernel<<<dim3(64, 16), 256, 0, stream>>>(w_qkvw, bt1, 1024, 4096);
  tcast_kernel<<<dim3(16, 16), 256, 0, stream>>>(w_out, bt2, 1024, 1024);

  if (rem >= full_need) {
    gemm256<bf16><<<dim3(16, 128), 512, 0, stream>>>(x_bf, bt1, qk, 4096, 1);
    attn_fuse<<<dim3(256, 4, 8), 256, 0, stream>>>(qk, owb, 0, (long)4096 * 4096);
  } else {
    for (int b = 0; b < 8; ++b) {
      gemm256<bf16><<<dim3(16, 16), 512, 0, stream>>>(
          x_bf + (size_t)b * 4096 * 1024, bt1, qk, 4096, 0);
      attn_fuse<<<dim3(256, 4, 1), 256, 0, stream>>>(qk, owb, b, 0);
    }
  }
  gemm256<float><<<dim3(4, 128), 512, 0, stream>>>(owb, bt2, out, 1024, 1);
}